// Round 16
// baseline (216.718 us; speedup 1.0000x reference)
//
#include <hip/hip_runtime.h>
#include <hip/hip_bf16.h>
#include <stdint.h>

#define N_NODES   50000
#define N_EDGES   800000
#define N_FEAT    512
#define HIDDEN    256
#define N_CLASSES 40
#define NPAD      48
#define SCAN_BLOCKS 196   // 196*256 = 50176 >= N_NODES

typedef __attribute__((ext_vector_type(8))) short short8;
typedef __attribute__((ext_vector_type(8))) __bf16 bf16x8;
typedef __attribute__((ext_vector_type(4))) float f32x4;
typedef __attribute__((ext_vector_type(2))) float f32x2;

__device__ inline unsigned short f2bf(float f) {
    unsigned int u = __builtin_bit_cast(unsigned int, f);
    u += 0x7FFFu + ((u >> 16) & 1u);   // RNE
    return (unsigned short)(u >> 16);
}
__device__ inline float bf2f(unsigned short s) {
    unsigned int u = ((unsigned int)s) << 16;
    return __builtin_bit_cast(float, u);
}

// async global->LDS, 16B per lane; lds ptr must be wave-uniform base
__device__ inline void gload16(const void* g, void* l) {
    typedef __attribute__((address_space(1))) const unsigned int gu32;
    typedef __attribute__((address_space(3))) unsigned int lu32;
    __builtin_amdgcn_global_load_lds((gu32*)g, (lu32*)l, 16, 0, 0);
}

// ---------------------------------------------------------------------------
// CSR build: zero -> histogram(+edge offset) -> hierarchical scan -> scatter
// ---------------------------------------------------------------------------
__global__ __launch_bounds__(256) void zero_kernel(int* __restrict__ counts) {
    int i = blockIdx.x * 256 + threadIdx.x;
    if (i < N_NODES) counts[i] = 0;
}

__global__ __launch_bounds__(256) void hist_kernel(const int* __restrict__ edge_dst,
                                                   int* __restrict__ counts,
                                                   int* __restrict__ eoff) {
    int e = blockIdx.x * 256 + threadIdx.x;
    if (e < N_EDGES) eoff[e] = atomicAdd(&counts[edge_dst[e]], 1);
}

__global__ __launch_bounds__(256) void block_sum_kernel(const int* __restrict__ counts,
                                                        int* __restrict__ bsums) {
    int i = blockIdx.x * 256 + threadIdx.x;
    int v = (i < N_NODES) ? counts[i] : 0;
#pragma unroll
    for (int off = 32; off > 0; off >>= 1) v += __shfl_xor(v, off, 64);
    __shared__ int ws[4];
    int lane = threadIdx.x & 63, w = threadIdx.x >> 6;
    if (lane == 0) ws[w] = v;
    __syncthreads();
    if (threadIdx.x == 0) bsums[blockIdx.x] = ws[0] + ws[1] + ws[2] + ws[3];
}

__global__ __launch_bounds__(256) void bsum_scan_kernel(const int* __restrict__ bsums,
                                                        int* __restrict__ boff,
                                                        int* __restrict__ row_ptr) {
    int t = threadIdx.x;
    int lane = t & 63, w = t >> 6;
    int v = (t < SCAN_BLOCKS) ? bsums[t] : 0;
    int inc = v;
#pragma unroll
    for (int off = 1; off < 64; off <<= 1) {
        int u = __shfl_up(inc, off, 64);
        if (lane >= off) inc += u;
    }
    __shared__ int wsum[4];
    if (lane == 63) wsum[w] = inc;
    __syncthreads();
    int add = 0;
    for (int j = 0; j < w; j++) add += wsum[j];
    if (t < SCAN_BLOCKS) boff[t] = add + inc - v;
    if (t == SCAN_BLOCKS - 1) row_ptr[N_NODES] = add + inc;
}

__global__ __launch_bounds__(256) void scan_apply_kernel(const int* __restrict__ counts,
                                                         const int* __restrict__ boff,
                                                         int* __restrict__ row_ptr) {
    int i = blockIdx.x * 256 + threadIdx.x;
    int lane = threadIdx.x & 63, w = threadIdx.x >> 6;
    int v = (i < N_NODES) ? counts[i] : 0;
    int inc = v;
#pragma unroll
    for (int off = 1; off < 64; off <<= 1) {
        int u = __shfl_up(inc, off, 64);
        if (lane >= off) inc += u;
    }
    __shared__ int wsum[4];
    if (lane == 63) wsum[w] = inc;
    __syncthreads();
    int add = 0;
    for (int j = 0; j < w; j++) add += wsum[j];
    if (i < N_NODES) row_ptr[i] = boff[blockIdx.x] + add + inc - v;
}

// scatter: atomic-free -> pos = row_ptr[dst] + eoff[e]; one fused 8B store
__global__ __launch_bounds__(256) void scatter_kernel(const int* __restrict__ edge_src,
                                                      const int* __restrict__ edge_dst,
                                                      const float* __restrict__ edge_w,
                                                      const int* __restrict__ rp,
                                                      const int* __restrict__ eoff,
                                                      int2* __restrict__ edge_srt) {
    int e = blockIdx.x * 256 + threadIdx.x;
    if (e >= N_EDGES) return;
    int pos = rp[edge_dst[e]] + eoff[e];
    int2 v;
    v.x = edge_src[e];
    v.y = __float_as_int(edge_w[e]);
    edge_srt[pos] = v;
}

// ---------------------------------------------------------------------------
// Weight prep
// ---------------------------------------------------------------------------
__global__ __launch_bounds__(256) void w1_tcast_kernel(const float* __restrict__ W1,
                                                       unsigned short* __restrict__ W1T) {
    int idx = blockIdx.x * 256 + threadIdx.x;      // 131072 total
    int k = idx >> 8, n = idx & 255;
    W1T[(size_t)n * N_FEAT + k] = f2bf(W1[idx]);
}

__global__ __launch_bounds__(256) void w2_tcast_kernel(const float* __restrict__ W2,
                                                       unsigned short* __restrict__ W2T) {
    int idx = blockIdx.x * 256 + threadIdx.x;      // 48*256 = 12288 total
    int n = idx >> 8, k = idx & 255;
    float v = (n < N_CLASSES) ? W2[k * N_CLASSES + n] : 0.f;
    W2T[idx] = f2bf(v);
}

// ---------------------------------------------------------------------------
// GEMM1 (bf16 MFMA): T1 fp8 = bf16(X f32) @ W1T^T
// tile BM=32 x BN=256, 4 waves (wave w: cols w*64..+64), grid 1563.
// A (shared by all waves) staged f32 via gload_lds (8 KB LDS only).
// B has ZERO inter-wave reuse -> read fragments DIRECTLY from L2-resident
// W1T (same 16B/lane gather gemm2 uses). 8 KB LDS -> up to 8 blocks/CU.
// ---------------------------------------------------------------------------
__global__ __launch_bounds__(256) void gemm1_mfma(const float* __restrict__ X,
                                                  const unsigned short* __restrict__ W1T,
                                                  unsigned char* __restrict__ T1f8) {
    __shared__ __align__(16) float As[32 * 64];    // 8 KB (f32)
    const int tid  = threadIdx.x;
    const int lane = tid & 63;
    const int w    = tid >> 6;
    const int m0   = blockIdx.x * 32;
    const int l15  = lane & 15;
    const int g    = lane >> 4;
    const int wbase = tid & ~63;     // wave-uniform slot base component

    f32x4 acc[2][4] = {};

    for (int k0 = 0; k0 < N_FEAT; k0 += 64) {
        __syncthreads();
        // A: 32 rows x 16 16B-chunks = 512 slots, 2 issues of 256
#pragma unroll
        for (int i = 0; i < 2; i++) {
            int slot = i * 256 + tid;
            int row = slot >> 4, c16 = slot & 15;
            int csrc = c16 ^ ((row & 7) << 1);
            int gm = m0 + row;
            if (gm > N_NODES - 1) gm = N_NODES - 1;   // clamp; masked at store
            gload16(&X[(size_t)gm * N_FEAT + k0 + csrc * 4],
                    &As[(size_t)(i * 256 + wbase) * 4]);
        }
        // B: direct global->reg fragments for this K-step (L2-resident W1T)
        bf16x8 bfr[2][4];
#pragma unroll
        for (int ko = 0; ko < 2; ko++) {
            int c = ko * 4 + g;
#pragma unroll
            for (int ni = 0; ni < 4; ni++) {
                int n = w * 64 + ni * 16 + l15;
                short8 s = *reinterpret_cast<const short8*>(
                    &W1T[(size_t)n * N_FEAT + k0 + c * 8]);
                bfr[ko][ni] = __builtin_bit_cast(bf16x8, s);
            }
        }
        asm volatile("s_waitcnt vmcnt(0)" ::: "memory");
        __syncthreads();
#pragma unroll
        for (int ko = 0; ko < 2; ko++) {             // two K=32 MFMAs per K-step
            int c = ko * 4 + g;                      // 8-bf16 k-chunk index
            bf16x8 a[2];
#pragma unroll
            for (int mi = 0; mi < 2; mi++) {
                int row = mi * 16 + l15;
                const float* pa = &As[row * 64 + ((2 * c) ^ ((row & 7) << 1)) * 4];
                float4 v0 = *reinterpret_cast<const float4*>(pa);
                float4 v1 = *reinterpret_cast<const float4*>(pa + 4);
                short8 s;
                s[0] = (short)f2bf(v0.x); s[1] = (short)f2bf(v0.y);
                s[2] = (short)f2bf(v0.z); s[3] = (short)f2bf(v0.w);
                s[4] = (short)f2bf(v1.x); s[5] = (short)f2bf(v1.y);
                s[6] = (short)f2bf(v1.z); s[7] = (short)f2bf(v1.w);
                a[mi] = __builtin_bit_cast(bf16x8, s);
            }
#pragma unroll
            for (int mi = 0; mi < 2; mi++)
#pragma unroll
                for (int ni = 0; ni < 4; ni++)
                    acc[mi][ni] = __builtin_amdgcn_mfma_f32_16x16x32_bf16(
                        a[mi], bfr[ko][ni], acc[mi][ni], 0, 0, 0);
        }
    }
    // epilogue: D[row=(g*4+r)][col=l15] -> T1 fp8 (HW cvt, OCP e4m3)
#pragma unroll
    for (int mi = 0; mi < 2; mi++) {
#pragma unroll
        for (int r = 0; r < 4; r++) {
            int gm = m0 + mi * 16 + g * 4 + r;
            if (gm < N_NODES) {
#pragma unroll
                for (int ni = 0; ni < 4; ni++) {
                    int n = w * 64 + ni * 16 + l15;
                    int pk = __builtin_amdgcn_cvt_pk_fp8_f32(acc[mi][ni][r],
                                                             acc[mi][ni][r], 0, false);
                    T1f8[(size_t)gm * HIDDEN + n] = (unsigned char)(pk & 0xff);
                }
            }
        }
    }
}

// ---------------------------------------------------------------------------
// FUSED SpMM1+relu+GEMM2: half-wave per dst node (8 nodes/block);
// h rows -> LDS (4 KB); wave 0 then does the 8x256x40 mini-GEMM (24 MFMA,
// W2T L1-resident) and writes T2 bf16 packed.
// ---------------------------------------------------------------------------
__global__ __launch_bounds__(256) void spmm_relu_gemm2_kernel(
        const unsigned char* __restrict__ T1f8,
        const int* __restrict__ rp,
        const int2* __restrict__ edges,
        const float* __restrict__ b1,
        const unsigned short* __restrict__ W2T,
        unsigned short* __restrict__ T2b) {
    __shared__ __align__(16) unsigned short hs[8][HIDDEN];   // 4 KB
    const int hw = threadIdx.x >> 5;                  // half-wave 0..7
    const int node = blockIdx.x * 8 + hw;             // 6250 * 8 = 50000 exact
    const int lane = threadIdx.x & 31;
    int s = rp[node], e = rp[node + 1];
    const int fo = lane * 8;                          // 8 fp8 = 8B per lane
    float a[8];
#pragma unroll
    for (int j = 0; j < 8; j++) a[j] = 0.f;
    int i = s;
    for (; i + 3 < e; i += 4) {
        int2 ed[4];
        uint2 p[4];
#pragma unroll
        for (int j = 0; j < 4; j++) ed[j] = edges[i + j];
#pragma unroll
        for (int j = 0; j < 4; j++)
            p[j] = *reinterpret_cast<const uint2*>(&T1f8[(size_t)ed[j].x * HIDDEN + fo]);
#pragma unroll
        for (int j = 0; j < 4; j++) {
            float w = __int_as_float(ed[j].y);
            f32x2 v0 = __builtin_amdgcn_cvt_pk_f32_fp8(p[j].x, false);
            f32x2 v1 = __builtin_amdgcn_cvt_pk_f32_fp8(p[j].x, true);
            f32x2 v2 = __builtin_amdgcn_cvt_pk_f32_fp8(p[j].y, false);
            f32x2 v3 = __builtin_amdgcn_cvt_pk_f32_fp8(p[j].y, true);
            a[0] += w * v0[0]; a[1] += w * v0[1];
            a[2] += w * v1[0]; a[3] += w * v1[1];
            a[4] += w * v2[0]; a[5] += w * v2[1];
            a[6] += w * v3[0]; a[7] += w * v3[1];
        }
    }
    for (; i < e; i++) {
        int2 e0 = edges[i];
        uint2 p0 = *reinterpret_cast<const uint2*>(&T1f8[(size_t)e0.x * HIDDEN + fo]);
        float w = __int_as_float(e0.y);
        f32x2 v0 = __builtin_amdgcn_cvt_pk_f32_fp8(p0.x, false);
        f32x2 v1 = __builtin_amdgcn_cvt_pk_f32_fp8(p0.x, true);
        f32x2 v2 = __builtin_amdgcn_cvt_pk_f32_fp8(p0.y, false);
        f32x2 v3 = __builtin_amdgcn_cvt_pk_f32_fp8(p0.y, true);
        a[0] += w * v0[0]; a[1] += w * v0[1];
        a[2] += w * v1[0]; a[3] += w * v1[1];
        a[4] += w * v2[0]; a[5] += w * v2[1];
        a[6] += w * v3[0]; a[7] += w * v3[1];
    }
    float4 bv0 = *reinterpret_cast<const float4*>(&b1[fo]);
    float4 bv1 = *reinterpret_cast<const float4*>(&b1[fo + 4]);
    a[0] = fmaxf(a[0] + bv0.x, 0.f);
    a[1] = fmaxf(a[1] + bv0.y, 0.f);
    a[2] = fmaxf(a[2] + bv0.z, 0.f);
    a[3] = fmaxf(a[3] + bv0.w, 0.f);
    a[4] = fmaxf(a[4] + bv1.x, 0.f);
    a[5] = fmaxf(a[5] + bv1.y, 0.f);
    a[6] = fmaxf(a[6] + bv1.z, 0.f);
    a[7] = fmaxf(a[7] + bv1.w, 0.f);
    uint4 o;
    o.x = (unsigned int)f2bf(a[0]) | ((unsigned int)f2bf(a[1]) << 16);
    o.y = (unsigned int)f2bf(a[2]) | ((unsigned int)f2bf(a[3]) << 16);
    o.z = (unsigned int)f2bf(a[4]) | ((unsigned int)f2bf(a[5]) << 16);
    o.w = (unsigned int)f2bf(a[6]) | ((unsigned int)f2bf(a[7]) << 16);
    *reinterpret_cast<uint4*>(&hs[hw][fo]) = o;
    __syncthreads();
    // wave 0: mini-GEMM 8x256x40 (rows 8..15 of A-frag zero)
    if (threadIdx.x < 64) {
        const int l15 = threadIdx.x & 15;
        const int g = threadIdx.x >> 4;
        f32x4 acc[3] = {};
#pragma unroll
        for (int k0 = 0; k0 < HIDDEN; k0 += 32) {
            bf16x8 af = {};
            if (l15 < 8) {
                short8 sa = *reinterpret_cast<const short8*>(&hs[l15][k0 + g * 8]);
                af = __builtin_bit_cast(bf16x8, sa);
            }
#pragma unroll
            for (int ni = 0; ni < 3; ni++) {
                short8 sb = *reinterpret_cast<const short8*>(
                    &W2T[(size_t)(ni * 16 + l15) * HIDDEN + k0 + g * 8]);
                bf16x8 bf = __builtin_bit_cast(bf16x8, sb);
                acc[ni] = __builtin_amdgcn_mfma_f32_16x16x32_bf16(af, bf, acc[ni], 0, 0, 0);
            }
        }
        // D: row = g*4+r (node within block, valid < 8), col = l15
#pragma unroll
        for (int ni = 0; ni < 3; ni++) {
#pragma unroll
            for (int r = 0; r < 4; r++) {
                int nd = g * 4 + r;
                int n = ni * 16 + l15;
                if (nd < 8 && n < N_CLASSES)
                    T2b[(size_t)(blockIdx.x * 8 + nd) * N_CLASSES + n] = f2bf(acc[ni][r]);
            }
        }
    }
}

// ---------------------------------------------------------------------------
// SpMM2 + bias + log_softmax: wave per dst node (4 per block), unroll x8
// T2 bf16 packed [M][40]; lanes >=40 clamp to class 0 (result discarded).
// ---------------------------------------------------------------------------
__global__ __launch_bounds__(256) void spmm_lsm_kernel(const unsigned short* __restrict__ T2b,
                                                       const int* __restrict__ rp,
                                                       const int2* __restrict__ edges,
                                                       const float* __restrict__ b2,
                                                       float* __restrict__ out) {
    int d = blockIdx.x * 4 + (threadIdx.x >> 6);
    int c = threadIdx.x & 63;
    bool act = c < N_CLASSES;
    int cc = act ? c : 0;
    int s = rp[d], e = rp[d + 1];
    float a0 = 0.f, a1 = 0.f, a2 = 0.f, a3 = 0.f;
    int i = s;
    for (; i + 7 < e; i += 8) {
        int2 ed[8];
        float v[8];
#pragma unroll
        for (int j = 0; j < 8; j++) ed[j] = edges[i + j];
#pragma unroll
        for (int j = 0; j < 8; j++)
            v[j] = bf2f(T2b[(size_t)ed[j].x * N_CLASSES + cc]);
        a0 += __int_as_float(ed[0].y) * v[0];
        a1 += __int_as_float(ed[1].y) * v[1];
        a2 += __int_as_float(ed[2].y) * v[2];
        a3 += __int_as_float(ed[3].y) * v[3];
        a0 += __int_as_float(ed[4].y) * v[4];
        a1 += __int_as_float(ed[5].y) * v[5];
        a2 += __int_as_float(ed[6].y) * v[6];
        a3 += __int_as_float(ed[7].y) * v[7];
    }
    for (; i < e; i++) {
        int2 e0 = edges[i];
        a0 += __int_as_float(e0.y) * bf2f(T2b[(size_t)e0.x * N_CLASSES + cc]);
    }
    float acc = (a0 + a1) + (a2 + a3);
    float z = act ? (acc + b2[c]) : -3.0e38f;
    float m = z;
#pragma unroll
    for (int off = 32; off > 0; off >>= 1) m = fmaxf(m, __shfl_xor(m, off, 64));
    float p = act ? __expf(z - m) : 0.f;
    float ssum = p;
#pragma unroll
    for (int off = 32; off > 0; off >>= 1) ssum += __shfl_xor(ssum, off, 64);
    if (act) out[(size_t)d * N_CLASSES + c] = z - m - __logf(ssum);
}

// ---------------------------------------------------------------------------
extern "C" void kernel_launch(void* const* d_in, const int* in_sizes, int n_in,
                              void* d_out, int out_size, void* d_ws, size_t ws_size,
                              hipStream_t stream) {
    const float* x    = (const float*)d_in[0];
    const int*   esrc = (const int*)d_in[1];
    const int*   edst = (const int*)d_in[2];
    const float* ew   = (const float*)d_in[3];
    const float* W1   = (const float*)d_in[4];
    const float* b1   = (const float*)d_in[5];
    const float* W2   = (const float*)d_in[6];
    const float* b2   = (const float*)d_in[7];
    float* out = (float*)d_out;

    // workspace carve (aligned 256B)
    uintptr_t p = (uintptr_t)d_ws;
    auto alloc = [&](size_t bytes) -> void* {
        void* r = (void*)p;
        p += (bytes + 255) & ~(size_t)255;
        return r;
    };
    unsigned char*  t1f8   = (unsigned char*)alloc((size_t)N_NODES * HIDDEN);      // 12.8 MB
    unsigned short* t2b    = (unsigned short*)alloc((size_t)N_NODES * N_CLASSES * 2); // 4 MB
    int*            counts = (int*)alloc((size_t)N_NODES * 4);
    int*            row_ptr= (int*)alloc((size_t)(N_NODES + 1) * 4);
    int*            eoff   = (int*)alloc((size_t)N_EDGES * 4);                     // 3.2 MB
    int2*           edge_srt = (int2*)alloc((size_t)N_EDGES * 8);                  // 6.4 MB
    unsigned short* W1Tb   = (unsigned short*)alloc((size_t)HIDDEN * N_FEAT * 2);  // 256 KB
    unsigned short* W2Tb   = (unsigned short*)alloc((size_t)NPAD * HIDDEN * 2);    // 24 KB
    int*            bsums  = (int*)alloc((size_t)SCAN_BLOCKS * 4);
    int*            boff   = (int*)alloc((size_t)SCAN_BLOCKS * 4);

    // --- CSR build + weight prep ---
    zero_kernel<<<SCAN_BLOCKS, 256, 0, stream>>>(counts);
    hist_kernel<<<(N_EDGES + 255) / 256, 256, 0, stream>>>(edst, counts, eoff);
    block_sum_kernel<<<SCAN_BLOCKS, 256, 0, stream>>>(counts, bsums);
    bsum_scan_kernel<<<1, 256, 0, stream>>>(bsums, boff, row_ptr);
    scan_apply_kernel<<<SCAN_BLOCKS, 256, 0, stream>>>(counts, boff, row_ptr);
    scatter_kernel<<<(N_EDGES + 255) / 256, 256, 0, stream>>>(esrc, edst, ew,
                                                              row_ptr, eoff, edge_srt);
    w1_tcast_kernel<<<(N_FEAT * HIDDEN) / 256, 256, 0, stream>>>(W1, W1Tb);
    w2_tcast_kernel<<<(NPAD * HIDDEN) / 256, 256, 0, stream>>>(W2, W2Tb);

    // --- Layer 1 (gemm) ---
    gemm1_mfma<<<(N_NODES + 31) / 32, 256, 0, stream>>>(x, W1Tb, t1f8);

    // --- Fused SpMM1+relu+GEMM2 ---
    spmm_relu_gemm2_kernel<<<N_NODES / 8, 256, 0, stream>>>(t1f8, row_ptr, edge_srt,
                                                            b1, W2Tb, t2b);

    // --- SpMM2 + log_softmax ---
    spmm_lsm_kernel<<<N_NODES / 4, 256, 0, stream>>>(t2b, row_ptr, edge_srt, b2, out);
}

// Round 18
// 186.652 us; speedup vs baseline: 1.1611x; 1.1611x over previous
//
#include <hip/hip_runtime.h>
#include <hip/hip_bf16.h>
#include <stdint.h>

#define N_NODES   50000
#define N_EDGES   800000
#define N_FEAT    512
#define HIDDEN    256
#define N_CLASSES 40
#define NPAD      48
#define SCAN_BLOCKS 196   // 196*256 = 50176 >= N_NODES

typedef __attribute__((ext_vector_type(8))) short short8;
typedef __attribute__((ext_vector_type(8))) __bf16 bf16x8;
typedef __attribute__((ext_vector_type(4))) float f32x4;
typedef __attribute__((ext_vector_type(2))) float f32x2;

__device__ inline unsigned short f2bf(float f) {
    unsigned int u = __builtin_bit_cast(unsigned int, f);
    u += 0x7FFFu + ((u >> 16) & 1u);   // RNE
    return (unsigned short)(u >> 16);
}
__device__ inline float bf2f(unsigned short s) {
    unsigned int u = ((unsigned int)s) << 16;
    return __builtin_bit_cast(float, u);
}

// async global->LDS, 16B per lane; lds ptr must be wave-uniform base
__device__ inline void gload16(const void* g, void* l) {
    typedef __attribute__((address_space(1))) const unsigned int gu32;
    typedef __attribute__((address_space(3))) unsigned int lu32;
    __builtin_amdgcn_global_load_lds((gu32*)g, (lu32*)l, 16, 0, 0);
}

// ---------------------------------------------------------------------------
// CSR build: zero -> histogram(+edge offset) -> hierarchical scan -> scatter
// ---------------------------------------------------------------------------
__global__ __launch_bounds__(256) void zero_kernel(int* __restrict__ counts) {
    int i = blockIdx.x * 256 + threadIdx.x;
    if (i < N_NODES) counts[i] = 0;
}

__global__ __launch_bounds__(256) void hist_kernel(const int* __restrict__ edge_dst,
                                                   int* __restrict__ counts,
                                                   int* __restrict__ eoff) {
    int e = blockIdx.x * 256 + threadIdx.x;
    if (e < N_EDGES) eoff[e] = atomicAdd(&counts[edge_dst[e]], 1);
}

__global__ __launch_bounds__(256) void block_sum_kernel(const int* __restrict__ counts,
                                                        int* __restrict__ bsums) {
    int i = blockIdx.x * 256 + threadIdx.x;
    int v = (i < N_NODES) ? counts[i] : 0;
#pragma unroll
    for (int off = 32; off > 0; off >>= 1) v += __shfl_xor(v, off, 64);
    __shared__ int ws[4];
    int lane = threadIdx.x & 63, w = threadIdx.x >> 6;
    if (lane == 0) ws[w] = v;
    __syncthreads();
    if (threadIdx.x == 0) bsums[blockIdx.x] = ws[0] + ws[1] + ws[2] + ws[3];
}

__global__ __launch_bounds__(256) void bsum_scan_kernel(const int* __restrict__ bsums,
                                                        int* __restrict__ boff,
                                                        int* __restrict__ row_ptr) {
    int t = threadIdx.x;
    int lane = t & 63, w = t >> 6;
    int v = (t < SCAN_BLOCKS) ? bsums[t] : 0;
    int inc = v;
#pragma unroll
    for (int off = 1; off < 64; off <<= 1) {
        int u = __shfl_up(inc, off, 64);
        if (lane >= off) inc += u;
    }
    __shared__ int wsum[4];
    if (lane == 63) wsum[w] = inc;
    __syncthreads();
    int add = 0;
    for (int j = 0; j < w; j++) add += wsum[j];
    if (t < SCAN_BLOCKS) boff[t] = add + inc - v;
    if (t == SCAN_BLOCKS - 1) row_ptr[N_NODES] = add + inc;
}

__global__ __launch_bounds__(256) void scan_apply_kernel(const int* __restrict__ counts,
                                                         const int* __restrict__ boff,
                                                         int* __restrict__ row_ptr) {
    int i = blockIdx.x * 256 + threadIdx.x;
    int lane = threadIdx.x & 63, w = threadIdx.x >> 6;
    int v = (i < N_NODES) ? counts[i] : 0;
    int inc = v;
#pragma unroll
    for (int off = 1; off < 64; off <<= 1) {
        int u = __shfl_up(inc, off, 64);
        if (lane >= off) inc += u;
    }
    __shared__ int wsum[4];
    if (lane == 63) wsum[w] = inc;
    __syncthreads();
    int add = 0;
    for (int j = 0; j < w; j++) add += wsum[j];
    if (i < N_NODES) row_ptr[i] = boff[blockIdx.x] + add + inc - v;
}

// scatter: atomic-free -> pos = row_ptr[dst] + eoff[e]; one fused 8B store
__global__ __launch_bounds__(256) void scatter_kernel(const int* __restrict__ edge_src,
                                                      const int* __restrict__ edge_dst,
                                                      const float* __restrict__ edge_w,
                                                      const int* __restrict__ rp,
                                                      const int* __restrict__ eoff,
                                                      int2* __restrict__ edge_srt) {
    int e = blockIdx.x * 256 + threadIdx.x;
    if (e >= N_EDGES) return;
    int pos = rp[edge_dst[e]] + eoff[e];
    int2 v;
    v.x = edge_src[e];
    v.y = __float_as_int(edge_w[e]);
    edge_srt[pos] = v;
}

// ---------------------------------------------------------------------------
// Weight prep
// ---------------------------------------------------------------------------
__global__ __launch_bounds__(256) void w1_tcast_kernel(const float* __restrict__ W1,
                                                       unsigned short* __restrict__ W1T) {
    int idx = blockIdx.x * 256 + threadIdx.x;      // 131072 total
    int k = idx >> 8, n = idx & 255;
    W1T[(size_t)n * N_FEAT + k] = f2bf(W1[idx]);
}

__global__ __launch_bounds__(256) void w2_tcast_kernel(const float* __restrict__ W2,
                                                       unsigned short* __restrict__ W2T) {
    int idx = blockIdx.x * 256 + threadIdx.x;      // 48*256 = 12288 total
    int n = idx >> 8, k = idx & 255;
    float v = (n < N_CLASSES) ? W2[k * N_CLASSES + n] : 0.f;
    W2T[idx] = f2bf(v);
}

// ---------------------------------------------------------------------------
// GEMM1 (bf16 MFMA): T1 fp8 = bf16(X f32) @ W1T^T
// tile BM=32 x BN=256, 4 waves (wave w: cols w*64..+64), grid 1563.
// A reg-staged: f32 global -> regs -> f2bf -> ds_write_b128 bf16 (4 KB LDS,
// 1 slot/thread, linear dest + pre-swizzled source chunk). B staged bf16
// via gload_lds (32 KB, coalesced - round-16 showed direct gather loses).
// Fragment reads: single ds_read_b128, no cvt in MFMA loop. LDS 36 KB.
// ---------------------------------------------------------------------------
__global__ __launch_bounds__(256) void gemm1_mfma(const float* __restrict__ X,
                                                  const unsigned short* __restrict__ W1T,
                                                  unsigned char* __restrict__ T1f8) {
    __shared__ __align__(16) unsigned short Asb[32 * 64];   // 4 KB (bf16)
    __shared__ __align__(16) unsigned short Bs[256 * 64];   // 32 KB (bf16)
    const int tid  = threadIdx.x;
    const int lane = tid & 63;
    const int w    = tid >> 6;
    const int m0   = blockIdx.x * 32;
    const int l15  = lane & 15;
    const int g    = lane >> 4;
    const int wbase = tid & ~63;     // wave-uniform slot base component

    // per-thread A staging indices (constant across K-steps)
    const int arow  = tid >> 3;               // 0..31
    const int acs   = tid & 7;                // dest chunk
    const int acsrc = acs ^ (arow & 7);       // pre-swizzled source chunk
    int agm = m0 + arow;
    if (agm > N_NODES - 1) agm = N_NODES - 1; // clamp; masked at store

    f32x4 acc[2][4] = {};

    for (int k0 = 0; k0 < N_FEAT; k0 += 64) {
        __syncthreads();
        // B: 256 rows x 8 16B-chunks = 2048 slots, 8 issues of 256 (async)
#pragma unroll
        for (int i = 0; i < 8; i++) {
            int slot = i * 256 + tid;
            int n = slot >> 3, cs = slot & 7;
            int csrc = cs ^ (n & 7);
            gload16(&W1T[(size_t)n * N_FEAT + k0 + csrc * 8],
                    &Bs[(size_t)(i * 256 + wbase) * 8]);
        }
        // A: reg-stage one 16B bf16 slot per thread (256 slots = 32x64 tile)
        {
            const float4* ps = reinterpret_cast<const float4*>(
                &X[(size_t)agm * N_FEAT + k0 + acsrc * 8]);
            float4 v0 = ps[0];
            float4 v1 = ps[1];
            short8 s;
            s[0] = (short)f2bf(v0.x); s[1] = (short)f2bf(v0.y);
            s[2] = (short)f2bf(v0.z); s[3] = (short)f2bf(v0.w);
            s[4] = (short)f2bf(v1.x); s[5] = (short)f2bf(v1.y);
            s[6] = (short)f2bf(v1.z); s[7] = (short)f2bf(v1.w);
            *reinterpret_cast<short8*>(&Asb[(size_t)tid * 8]) = s;
        }
        asm volatile("s_waitcnt vmcnt(0)" ::: "memory");
        __syncthreads();
#pragma unroll
        for (int ko = 0; ko < 2; ko++) {             // two K=32 MFMAs per K-step
            int c = ko * 4 + g;                      // 8-bf16 k-chunk index
            bf16x8 a[2];
            bf16x8 b[4];
#pragma unroll
            for (int mi = 0; mi < 2; mi++) {
                int row = mi * 16 + l15;
                short8 s = *reinterpret_cast<const short8*>(
                    &Asb[(row * 8 + (c ^ (row & 7))) * 8]);
                a[mi] = __builtin_bit_cast(bf16x8, s);
            }
#pragma unroll
            for (int ni = 0; ni < 4; ni++) {
                int n = w * 64 + ni * 16 + l15;
                short8 s = *reinterpret_cast<const short8*>(
                    &Bs[(n * 8 + (c ^ (n & 7))) * 8]);
                b[ni] = __builtin_bit_cast(bf16x8, s);
            }
#pragma unroll
            for (int mi = 0; mi < 2; mi++)
#pragma unroll
                for (int ni = 0; ni < 4; ni++)
                    acc[mi][ni] = __builtin_amdgcn_mfma_f32_16x16x32_bf16(
                        a[mi], b[ni], acc[mi][ni], 0, 0, 0);
        }
    }
    // epilogue: D[row=(g*4+r)][col=l15] -> T1 fp8 (HW cvt, OCP e4m3)
#pragma unroll
    for (int mi = 0; mi < 2; mi++) {
#pragma unroll
        for (int r = 0; r < 4; r++) {
            int gm = m0 + mi * 16 + g * 4 + r;
            if (gm < N_NODES) {
#pragma unroll
                for (int ni = 0; ni < 4; ni++) {
                    int n = w * 64 + ni * 16 + l15;
                    int pk = __builtin_amdgcn_cvt_pk_fp8_f32(acc[mi][ni][r],
                                                             acc[mi][ni][r], 0, false);
                    T1f8[(size_t)gm * HIDDEN + n] = (unsigned char)(pk & 0xff);
                }
            }
        }
    }
}

// ---------------------------------------------------------------------------
// FUSED SpMM1+relu+GEMM2: half-wave per dst node (8 nodes/block);
// h rows -> LDS (4 KB); wave 0 then does the 8x256x40 mini-GEMM (24 MFMA,
// W2T L1-resident) and writes T2 bf16 packed.
// ---------------------------------------------------------------------------
__global__ __launch_bounds__(256) void spmm_relu_gemm2_kernel(
        const unsigned char* __restrict__ T1f8,
        const int* __restrict__ rp,
        const int2* __restrict__ edges,
        const float* __restrict__ b1,
        const unsigned short* __restrict__ W2T,
        unsigned short* __restrict__ T2b) {
    __shared__ __align__(16) unsigned short hs[8][HIDDEN];   // 4 KB
    const int hw = threadIdx.x >> 5;                  // half-wave 0..7
    const int node = blockIdx.x * 8 + hw;             // 6250 * 8 = 50000 exact
    const int lane = threadIdx.x & 31;
    int s = rp[node], e = rp[node + 1];
    const int fo = lane * 8;                          // 8 fp8 = 8B per lane
    float a[8];
#pragma unroll
    for (int j = 0; j < 8; j++) a[j] = 0.f;
    int i = s;
    for (; i + 3 < e; i += 4) {
        int2 ed[4];
        uint2 p[4];
#pragma unroll
        for (int j = 0; j < 4; j++) ed[j] = edges[i + j];
#pragma unroll
        for (int j = 0; j < 4; j++)
            p[j] = *reinterpret_cast<const uint2*>(&T1f8[(size_t)ed[j].x * HIDDEN + fo]);
#pragma unroll
        for (int j = 0; j < 4; j++) {
            float w = __int_as_float(ed[j].y);
            f32x2 v0 = __builtin_amdgcn_cvt_pk_f32_fp8(p[j].x, false);
            f32x2 v1 = __builtin_amdgcn_cvt_pk_f32_fp8(p[j].x, true);
            f32x2 v2 = __builtin_amdgcn_cvt_pk_f32_fp8(p[j].y, false);
            f32x2 v3 = __builtin_amdgcn_cvt_pk_f32_fp8(p[j].y, true);
            a[0] += w * v0[0]; a[1] += w * v0[1];
            a[2] += w * v1[0]; a[3] += w * v1[1];
            a[4] += w * v2[0]; a[5] += w * v2[1];
            a[6] += w * v3[0]; a[7] += w * v3[1];
        }
    }
    for (; i < e; i++) {
        int2 e0 = edges[i];
        uint2 p0 = *reinterpret_cast<const uint2*>(&T1f8[(size_t)e0.x * HIDDEN + fo]);
        float w = __int_as_float(e0.y);
        f32x2 v0 = __builtin_amdgcn_cvt_pk_f32_fp8(p0.x, false);
        f32x2 v1 = __builtin_amdgcn_cvt_pk_f32_fp8(p0.x, true);
        f32x2 v2 = __builtin_amdgcn_cvt_pk_f32_fp8(p0.y, false);
        f32x2 v3 = __builtin_amdgcn_cvt_pk_f32_fp8(p0.y, true);
        a[0] += w * v0[0]; a[1] += w * v0[1];
        a[2] += w * v1[0]; a[3] += w * v1[1];
        a[4] += w * v2[0]; a[5] += w * v2[1];
        a[6] += w * v3[0]; a[7] += w * v3[1];
    }
    float4 bv0 = *reinterpret_cast<const float4*>(&b1[fo]);
    float4 bv1 = *reinterpret_cast<const float4*>(&b1[fo + 4]);
    a[0] = fmaxf(a[0] + bv0.x, 0.f);
    a[1] = fmaxf(a[1] + bv0.y, 0.f);
    a[2] = fmaxf(a[2] + bv0.z, 0.f);
    a[3] = fmaxf(a[3] + bv0.w, 0.f);
    a[4] = fmaxf(a[4] + bv1.x, 0.f);
    a[5] = fmaxf(a[5] + bv1.y, 0.f);
    a[6] = fmaxf(a[6] + bv1.z, 0.f);
    a[7] = fmaxf(a[7] + bv1.w, 0.f);
    uint4 o;
    o.x = (unsigned int)f2bf(a[0]) | ((unsigned int)f2bf(a[1]) << 16);
    o.y = (unsigned int)f2bf(a[2]) | ((unsigned int)f2bf(a[3]) << 16);
    o.z = (unsigned int)f2bf(a[4]) | ((unsigned int)f2bf(a[5]) << 16);
    o.w = (unsigned int)f2bf(a[6]) | ((unsigned int)f2bf(a[7]) << 16);
    *reinterpret_cast<uint4*>(&hs[hw][fo]) = o;
    __syncthreads();
    // wave 0: mini-GEMM 8x256x40 (rows 8..15 of A-frag zero)
    if (threadIdx.x < 64) {
        const int l15 = threadIdx.x & 15;
        const int g = threadIdx.x >> 4;
        f32x4 acc[3] = {};
#pragma unroll
        for (int k0 = 0; k0 < HIDDEN; k0 += 32) {
            bf16x8 af = {};
            if (l15 < 8) {
                short8 sa = *reinterpret_cast<const short8*>(&hs[l15][k0 + g * 8]);
                af = __builtin_bit_cast(bf16x8, sa);
            }
#pragma unroll
            for (int ni = 0; ni < 3; ni++) {
                short8 sb = *reinterpret_cast<const short8*>(
                    &W2T[(size_t)(ni * 16 + l15) * HIDDEN + k0 + g * 8]);
                bf16x8 bf = __builtin_bit_cast(bf16x8, sb);
                acc[ni] = __builtin_amdgcn_mfma_f32_16x16x32_bf16(af, bf, acc[ni], 0, 0, 0);
            }
        }
        // D: row = g*4+r (node within block, valid < 8), col = l15
#pragma unroll
        for (int ni = 0; ni < 3; ni++) {
#pragma unroll
            for (int r = 0; r < 4; r++) {
                int nd = g * 4 + r;
                int n = ni * 16 + l15;
                if (nd < 8 && n < N_CLASSES)
                    T2b[(size_t)(blockIdx.x * 8 + nd) * N_CLASSES + n] = f2bf(acc[ni][r]);
            }
        }
    }
}

// ---------------------------------------------------------------------------
// SpMM2 + bias + log_softmax: wave per dst node (4 per block), unroll x8
// T2 bf16 packed [M][40]; lanes >=40 clamp to class 0 (result discarded).
// ---------------------------------------------------------------------------
__global__ __launch_bounds__(256) void spmm_lsm_kernel(const unsigned short* __restrict__ T2b,
                                                       const int* __restrict__ rp,
                                                       const int2* __restrict__ edges,
                                                       const float* __restrict__ b2,
                                                       float* __restrict__ out) {
    int d = blockIdx.x * 4 + (threadIdx.x >> 6);
    int c = threadIdx.x & 63;
    bool act = c < N_CLASSES;
    int cc = act ? c : 0;
    int s = rp[d], e = rp[d + 1];
    float a0 = 0.f, a1 = 0.f, a2 = 0.f, a3 = 0.f;
    int i = s;
    for (; i + 7 < e; i += 8) {
        int2 ed[8];
        float v[8];
#pragma unroll
        for (int j = 0; j < 8; j++) ed[j] = edges[i + j];
#pragma unroll
        for (int j = 0; j < 8; j++)
            v[j] = bf2f(T2b[(size_t)ed[j].x * N_CLASSES + cc]);
        a0 += __int_as_float(ed[0].y) * v[0];
        a1 += __int_as_float(ed[1].y) * v[1];
        a2 += __int_as_float(ed[2].y) * v[2];
        a3 += __int_as_float(ed[3].y) * v[3];
        a0 += __int_as_float(ed[4].y) * v[4];
        a1 += __int_as_float(ed[5].y) * v[5];
        a2 += __int_as_float(ed[6].y) * v[6];
        a3 += __int_as_float(ed[7].y) * v[7];
    }
    for (; i < e; i++) {
        int2 e0 = edges[i];
        a0 += __int_as_float(e0.y) * bf2f(T2b[(size_t)e0.x * N_CLASSES + cc]);
    }
    float acc = (a0 + a1) + (a2 + a3);
    float z = act ? (acc + b2[c]) : -3.0e38f;
    float m = z;
#pragma unroll
    for (int off = 32; off > 0; off >>= 1) m = fmaxf(m, __shfl_xor(m, off, 64));
    float p = act ? __expf(z - m) : 0.f;
    float ssum = p;
#pragma unroll
    for (int off = 32; off > 0; off >>= 1) ssum += __shfl_xor(ssum, off, 64);
    if (act) out[(size_t)d * N_CLASSES + c] = z - m - __logf(ssum);
}

// ---------------------------------------------------------------------------
extern "C" void kernel_launch(void* const* d_in, const int* in_sizes, int n_in,
                              void* d_out, int out_size, void* d_ws, size_t ws_size,
                              hipStream_t stream) {
    const float* x    = (const float*)d_in[0];
    const int*   esrc = (const int*)d_in[1];
    const int*   edst = (const int*)d_in[2];
    const float* ew   = (const float*)d_in[3];
    const float* W1   = (const float*)d_in[4];
    const float* b1   = (const float*)d_in[5];
    const float* W2   = (const float*)d_in[6];
    const float* b2   = (const float*)d_in[7];
    float* out = (float*)d_out;

    // workspace carve (aligned 256B)
    uintptr_t p = (uintptr_t)d_ws;
    auto alloc = [&](size_t bytes) -> void* {
        void* r = (void*)p;
        p += (bytes + 255) & ~(size_t)255;
        return r;
    };
    unsigned char*  t1f8   = (unsigned char*)alloc((size_t)N_NODES * HIDDEN);      // 12.8 MB
    unsigned short* t2b    = (unsigned short*)alloc((size_t)N_NODES * N_CLASSES * 2); // 4 MB
    int*            counts = (int*)alloc((size_t)N_NODES * 4);
    int*            row_ptr= (int*)alloc((size_t)(N_NODES + 1) * 4);
    int*            eoff   = (int*)alloc((size_t)N_EDGES * 4);                     // 3.2 MB
    int2*           edge_srt = (int2*)alloc((size_t)N_EDGES * 8);                  // 6.4 MB
    unsigned short* W1Tb   = (unsigned short*)alloc((size_t)HIDDEN * N_FEAT * 2);  // 256 KB
    unsigned short* W2Tb   = (unsigned short*)alloc((size_t)NPAD * HIDDEN * 2);    // 24 KB
    int*            bsums  = (int*)alloc((size_t)SCAN_BLOCKS * 4);
    int*            boff   = (int*)alloc((size_t)SCAN_BLOCKS * 4);

    // --- CSR build + weight prep ---
    zero_kernel<<<SCAN_BLOCKS, 256, 0, stream>>>(counts);
    hist_kernel<<<(N_EDGES + 255) / 256, 256, 0, stream>>>(edst, counts, eoff);
    block_sum_kernel<<<SCAN_BLOCKS, 256, 0, stream>>>(counts, bsums);
    bsum_scan_kernel<<<1, 256, 0, stream>>>(bsums, boff, row_ptr);
    scan_apply_kernel<<<SCAN_BLOCKS, 256, 0, stream>>>(counts, boff, row_ptr);
    scatter_kernel<<<(N_EDGES + 255) / 256, 256, 0, stream>>>(esrc, edst, ew,
                                                              row_ptr, eoff, edge_srt);
    w1_tcast_kernel<<<(N_FEAT * HIDDEN) / 256, 256, 0, stream>>>(W1, W1Tb);
    w2_tcast_kernel<<<(NPAD * HIDDEN) / 256, 256, 0, stream>>>(W2, W2Tb);

    // --- Layer 1 (gemm) ---
    gemm1_mfma<<<(N_NODES + 31) / 32, 256, 0, stream>>>(x, W1Tb, t1f8);

    // --- Fused SpMM1+relu+GEMM2 ---
    spmm_relu_gemm2_kernel<<<N_NODES / 8, 256, 0, stream>>>(t1f8, row_ptr, edge_srt,
                                                            b1, W2Tb, t2b);

    // --- SpMM2 + log_softmax ---
    spmm_lsm_kernel<<<N_NODES / 4, 256, 0, stream>>>(t2b, row_ptr, edge_srt, b2, out);
}